// Round 1
// 418.564 us; speedup vs baseline: 1.1220x; 1.1220x over previous
//
#include <hip/hip_runtime.h>
#include <hip/hip_bf16.h>
#include <stdint.h>
#include <stddef.h>

#define Bdim  32
#define Sdim  1024
#define Hdim  1024
#define Wdim  128
#define Ktok  6
#define NHEAD 16
#define HDdim 64
#define Lgrp  (Bdim*Wdim)      // 4096 groups
#define Mrows (Lgrp*Ktok)      // 24576 gathered rows
#define Ncols (2*Hdim)         // 2048 (q|k)
#define CVTROWS (Mrows + Ncols)

// 8-phase GEMM geometry (m201 template)
#define BMg 256
#define BNg 256
#define BKg 64
#define NKT (Hdim/BKg)         // 16 K-tiles

typedef __attribute__((ext_vector_type(8))) short short8;
typedef __attribute__((ext_vector_type(4))) short short4_t;
typedef __attribute__((ext_vector_type(4))) float floatx4;
typedef __hip_bfloat16 bf16_t;

typedef unsigned int u32_g __attribute__((address_space(1)));
typedef unsigned int u32_l __attribute__((address_space(3)));

__device__ __forceinline__ void gld_lds16(const void* g, void* l) {
    __builtin_amdgcn_global_load_lds((const u32_g*)g, (u32_l*)l, 16, 0, 0);
}

__device__ __forceinline__ float b2f(short s) {
    union { float f; unsigned u; } x; x.u = ((unsigned)(unsigned short)s) << 16; return x.f;
}

// pack 8 fp32 -> 8 bf16 (RNE) in a 16B vector
__device__ __forceinline__ short8 cvt8(const float4 lo, const float4 hi) {
    union { short8 s; bf16_t h[8]; } u;
    u.h[0] = __float2bfloat16(lo.x); u.h[1] = __float2bfloat16(lo.y);
    u.h[2] = __float2bfloat16(lo.z); u.h[3] = __float2bfloat16(lo.w);
    u.h[4] = __float2bfloat16(hi.x); u.h[5] = __float2bfloat16(hi.y);
    u.h[6] = __float2bfloat16(hi.z); u.h[7] = __float2bfloat16(hi.w);
    return u.s;
}

// ---------------------------------------------------------------------------
// st_16x32 swizzled half-tile addressing (128 rows x 64 cols bf16, 16 KiB).
// Layout: 8x2 subtiles of 16 rows x 32 cols (1024 B each), row-major subtile
// order; within a subtile, col-bit4 is XOR'd with row-bit3 (bank spread for
// the 16-lane column-slice ds_read_b128 -> ~4-way residual, m201).
// ---------------------------------------------------------------------------
__device__ __forceinline__ int lds_ro(int row, int col) {
    const int sub = ((row >> 4) << 1) | (col >> 5);
    const int c   = (col & 31) ^ (((row >> 3) & 1) << 4);
    return (sub << 10) | ((row & 15) << 6) | (c << 1);
}
// inverse map: linear staging byte offset p -> logical (row,col). Used to
// pre-swizzle the GLOBAL source address (global_load_lds dest stays linear).
__device__ __forceinline__ void stg_map(int p, int& row, int& col) {
    const int r16 = (p >> 6) & 15;
    int c = (p >> 1) & 31;
    c ^= ((r16 >> 3) & 1) << 4;
    row = ((p >> 11) << 4) | r16;
    col = (((p >> 10) & 1) << 5) | c;
}

// ---------------------------------------------------------------------------
// Kernel 0 (fast path): gather A rows + convert everything to bf16 once.
// ---------------------------------------------------------------------------
__global__ void gather_cvt(const float* __restrict__ TE, const float* __restrict__ Wt,
                           const int* __restrict__ sidx,
                           bf16_t* __restrict__ Xa, bf16_t* __restrict__ Wb)
{
    const int r = blockIdx.x;
    const int t = threadIdx.x;
    const float* src;
    bf16_t* dst;
    if (r < Mrows) {
        src = TE + ((size_t)(r/768)*Sdim + sidx[r])*Hdim;
        dst = Xa + (size_t)r*Hdim;
    } else {
        src = Wt + (size_t)(r - Mrows)*Hdim;
        dst = Wb + (size_t)(r - Mrows)*Hdim;
    }
    const float4 v = *(const float4*)(src + t*4);
    union { short4_t s; bf16_t h[4]; } u;
    u.h[0] = __float2bfloat16(v.x); u.h[1] = __float2bfloat16(v.y);
    u.h[2] = __float2bfloat16(v.z); u.h[3] = __float2bfloat16(v.w);
    *(short4_t*)(dst + t*4) = u.s;
}

// ---------------------------------------------------------------------------
// Kernel 1 (fast path): 256x256 8-phase pipelined bf16 GEMM. C = Xa*Wb^T + b.
// 8 waves (2M x 4N), BK=64, 128 KiB LDS as [2 dbuf][A/B][2 half][16 KiB].
// Per phase: one 128x128 block-quadrant x K=64 (16 MFMA/wave), 1 half-tile
// global_load_lds prefetch, raw barriers, counted vmcnt (never 0 mid-loop).
// Half-tile pipeline (quadrant order Q00,Q01,Q11,Q10):
//   A0 free after ph2, B1 after ph3, A1/B0 after ph4 =>
//   stage A1(u+1)@u.1, B0(u+1)@u.2, A0(u+2)@u.3, B1(u+2)@u.4.
//   Steady in-flight at tile boundary = {A0,B1}(u+2) = 4 loads => vmcnt(4).
// ---------------------------------------------------------------------------
__global__ __launch_bounds__(512, 2) void gemm_8ph(
    const bf16_t* __restrict__ Xa, const bf16_t* __restrict__ Wb,
    const float* __restrict__ bias, bf16_t* __restrict__ Cq)
{
    __shared__ __align__(16) char lds[2][2][2][16384];
    const int tid  = threadIdx.x;
    const int lane = tid & 63;
    const int wv   = tid >> 6;
    const int wr   = wv >> 2;      // 0..1
    const int wc   = wv & 3;       // 0..3
    const int fr   = lane & 15;
    const int fq   = lane >> 4;

    // bijective XCD swizzle (768 % 8 == 0): 96 consecutive tiles per XCD,
    // col-tile-fast => 4 concurrent A row-panels + all of B per XCD L2.
    const int cpx  = gridDim.x >> 3;
    const int orig = blockIdx.x;
    const int swz  = (orig & 7) * cpx + (orig >> 3);
    const int tileM = (swz >> 3) * BMg;
    const int tileN = (swz & 7) * BNg;

    int r0, c0, r1, c1;
    stg_map(tid * 16, r0, c0);
    stg_map(8192 + tid * 16, r1, c1);

    const bf16_t* srcA = Xa + (size_t)tileM * Hdim;
    const bf16_t* srcB = Wb + (size_t)tileN * Hdim;

    int aoff[4][2], boff[2][2];
    #pragma unroll
    for (int mi = 0; mi < 4; mi++)
        #pragma unroll
        for (int ks = 0; ks < 2; ks++)
            aoff[mi][ks] = lds_ro(wr*64 + mi*16 + fr, ks*32 + fq*8);
    #pragma unroll
    for (int ni = 0; ni < 2; ni++)
        #pragma unroll
        for (int ks = 0; ks < 2; ks++)
            boff[ni][ks] = lds_ro(wc*32 + ni*16 + fr, ks*32 + fq*8);

    short8 a[4][2], b[2][2];
    floatx4 acc[2][2][4][2] = {};

#define STAGE(bufi, isB, half, kt) do { \
        const bf16_t* _s = (isB) ? srcB : srcA; \
        char* _d = &lds[(bufi)][(isB)][(half)][0]; \
        const int _kb = (kt) * BKg; \
        gld_lds16(_s + (size_t)((half)*128 + r0) * Hdim + _kb + c0, _d + tid*16); \
        gld_lds16(_s + (size_t)((half)*128 + r1) * Hdim + _kb + c1, _d + 8192 + tid*16); \
    } while (0)

#define LDAf(bufi, qr) do { \
        const char* _sA = &lds[(bufi)][0][(qr)][0]; \
        _Pragma("unroll") \
        for (int mi = 0; mi < 4; mi++) { \
            a[mi][0] = *(const short8*)(const void*)(_sA + aoff[mi][0]); \
            a[mi][1] = *(const short8*)(const void*)(_sA + aoff[mi][1]); \
        } \
    } while (0)

#define LDBf(bufi, qc) do { \
        const char* _sB = &lds[(bufi)][1][(qc)][0]; \
        _Pragma("unroll") \
        for (int ni = 0; ni < 2; ni++) { \
            b[ni][0] = *(const short8*)(const void*)(_sB + boff[ni][0]); \
            b[ni][1] = *(const short8*)(const void*)(_sB + boff[ni][1]); \
        } \
    } while (0)

#define MMA(qr, qc) do { \
        __builtin_amdgcn_s_setprio(1); \
        _Pragma("unroll") \
        for (int mi = 0; mi < 4; mi++) \
            _Pragma("unroll") \
            for (int ni = 0; ni < 2; ni++) { \
                acc[qr][qc][mi][ni] = __builtin_amdgcn_mfma_f32_16x16x32_bf16( \
                    a[mi][0], b[ni][0], acc[qr][qc][mi][ni], 0, 0, 0); \
                acc[qr][qc][mi][ni] = __builtin_amdgcn_mfma_f32_16x16x32_bf16( \
                    a[mi][1], b[ni][1], acc[qr][qc][mi][ni], 0, 0, 0); \
            } \
        __builtin_amdgcn_s_setprio(0); \
    } while (0)

#define WAIT_LGKM() asm volatile("s_waitcnt lgkmcnt(0)" ::: "memory")

    // prologue: A0(0) B1(0) A1(0) B0(0) A0(1) B1(1); tile0 landed, 4 in flight
    STAGE(0, 0, 0, 0);
    STAGE(0, 1, 1, 0);
    STAGE(0, 0, 1, 0);
    STAGE(0, 1, 0, 0);
    STAGE(1, 0, 0, 1);
    STAGE(1, 1, 1, 1);
    asm volatile("s_waitcnt vmcnt(4)" ::: "memory");
    __builtin_amdgcn_s_barrier();

    for (int u = 0; u < NKT; ++u) {
        const int bf = u & 1;
        const int nb = bf ^ 1;
        // phase 1: Q(0,0) — read A0,B0 (12 ds_reads); stage A1(u+1)
        LDAf(bf, 0); LDBf(bf, 0);
        if (u + 1 < NKT) STAGE(nb, 0, 1, u + 1);
        __builtin_amdgcn_s_barrier();
        WAIT_LGKM();
        MMA(0, 0);
        __builtin_amdgcn_s_barrier();
        // phase 2: Q(0,1) — reuse a, read B1; stage B0(u+1)
        LDBf(bf, 1);
        if (u + 1 < NKT) STAGE(nb, 1, 0, u + 1);
        __builtin_amdgcn_s_barrier();
        WAIT_LGKM();
        MMA(0, 1);
        __builtin_amdgcn_s_barrier();
        // phase 3: Q(1,1) — reuse b, read A1; stage A0(u+2) (A0 freed @ph2)
        LDAf(bf, 1);
        if (u + 2 < NKT) STAGE(bf, 0, 0, u + 2);
        __builtin_amdgcn_s_barrier();
        WAIT_LGKM();
        MMA(1, 1);
        __builtin_amdgcn_s_barrier();
        // phase 4: Q(1,0) — reuse a, re-read B0; stage B1(u+2) (B1 freed @ph3)
        LDBf(bf, 0);
        if (u + 2 < NKT) STAGE(bf, 1, 1, u + 2);
        __builtin_amdgcn_s_barrier();
        WAIT_LGKM();
        MMA(1, 0);
        // counted wait: tile u+1 fully landed, {A0,B1}(u+2) stay in flight
        if (u + 2 < NKT)      asm volatile("s_waitcnt vmcnt(4)" ::: "memory");
        else if (u + 1 < NKT) asm volatile("s_waitcnt vmcnt(0)" ::: "memory");
        __builtin_amdgcn_s_barrier();
    }

    #pragma unroll
    for (int qr = 0; qr < 2; qr++)
      #pragma unroll
      for (int qc = 0; qc < 2; qc++)
        #pragma unroll
        for (int ni = 0; ni < 2; ni++) {
            const int col = tileN + qc*128 + wc*32 + ni*16 + fr;
            const float bv = bias[col];
            #pragma unroll
            for (int mi = 0; mi < 4; mi++)
              #pragma unroll
              for (int j = 0; j < 4; j++) {
                const int row = tileM + qr*128 + wr*64 + mi*16 + fq*4 + j;
                Cq[(size_t)row * Ncols + col] = __float2bfloat16(acc[qr][qc][mi][ni][j] + bv);
              }
        }
#undef STAGE
#undef LDAf
#undef LDBf
#undef MMA
#undef WAIT_LGKM
}

// ---------------------------------------------------------------------------
// Kernel 1 (fallback, ws too small): fused gather+cvt GEMM (128-tile).
// ---------------------------------------------------------------------------
__global__ __launch_bounds__(256, 2) void gemm_qk(
    const float* __restrict__ TE, const float* __restrict__ Wt,
    const float* __restrict__ bias, const int* __restrict__ sidx,
    bf16_t* __restrict__ Cq)
{
    __shared__ __align__(16) bf16_t As[128*32];
    __shared__ __align__(16) bf16_t Bs[128*32];
    const int tid  = threadIdx.x;
    const int wv   = tid >> 6;
    const int lane = tid & 63;
    const int tileM = blockIdx.x * 128;
    const int tileN = blockIdx.y * 128;

    const int r0 = wv*32 + (lane>>2);
    const int r1 = r0 + 16;
    const int c8 = (lane&3)*8;

    const int m0 = tileM + r0;
    const int m1 = tileM + r1;
    const float* pA0 = TE + ((size_t)(m0/768)*Sdim + sidx[m0])*Hdim + c8;
    const float* pA1 = TE + ((size_t)(m1/768)*Sdim + sidx[m1])*Hdim + c8;
    const float* pB0 = Wt + (size_t)(tileN + r0)*Hdim + c8;
    const float* pB1 = Wt + (size_t)(tileN + r1)*Hdim + c8;
    bf16_t* lA0 = &As[r0*32 + c8];
    bf16_t* lA1 = &As[r1*32 + c8];
    bf16_t* lB0 = &Bs[r0*32 + c8];
    bf16_t* lB1 = &Bs[r1*32 + c8];

    const int wm = (wv & 1)*64;
    const int wn = (wv >> 1)*64;
    const int fr = lane & 15;
    const int fq = lane >> 4;

    floatx4 acc[4][4] = {};

    for (int k0 = 0; k0 < Hdim; k0 += 32) {
        const float4 a0l = *(const float4*)(pA0 + k0);
        const float4 a0h = *(const float4*)(pA0 + k0 + 4);
        const float4 a1l = *(const float4*)(pA1 + k0);
        const float4 a1h = *(const float4*)(pA1 + k0 + 4);
        const float4 b0l = *(const float4*)(pB0 + k0);
        const float4 b0h = *(const float4*)(pB0 + k0 + 4);
        const float4 b1l = *(const float4*)(pB1 + k0);
        const float4 b1h = *(const float4*)(pB1 + k0 + 4);
        *(short8*)(void*)lA0 = cvt8(a0l, a0h);
        *(short8*)(void*)lA1 = cvt8(a1l, a1h);
        *(short8*)(void*)lB0 = cvt8(b0l, b0h);
        *(short8*)(void*)lB1 = cvt8(b1l, b1h);
        __syncthreads();
        short8 a[4], b[4];
        #pragma unroll
        for (int mi = 0; mi < 4; mi++)
            a[mi] = *(const short8*)(const void*)&As[(wm + mi*16 + fr)*32 + fq*8];
        #pragma unroll
        for (int ni = 0; ni < 4; ni++)
            b[ni] = *(const short8*)(const void*)&Bs[(wn + ni*16 + fr)*32 + fq*8];
        #pragma unroll
        for (int mi = 0; mi < 4; mi++)
            #pragma unroll
            for (int ni = 0; ni < 4; ni++)
                acc[mi][ni] = __builtin_amdgcn_mfma_f32_16x16x32_bf16(
                    a[mi], b[ni], acc[mi][ni], 0, 0, 0);
        __syncthreads();
    }

    #pragma unroll
    for (int ni = 0; ni < 4; ni++) {
        const int col = tileN + wn + ni*16 + fr;
        const float bv = bias[col];
        #pragma unroll
        for (int mi = 0; mi < 4; mi++) {
            #pragma unroll
            for (int r = 0; r < 4; r++) {
                const int row = tileM + wm + mi*16 + fq*4 + r;
                Cq[(size_t)row * Ncols + col] = __float2bfloat16(acc[mi][ni][r] + bv);
            }
        }
    }
}

// ---------------------------------------------------------------------------
// Kernel 2: out = token_embeddings (full fp32 copy, 16B vectors)
// ---------------------------------------------------------------------------
__global__ void copy_te(const uint4* __restrict__ src, uint4* __restrict__ dst, int n)
{
    int i = blockIdx.x * blockDim.x + threadIdx.x;
    const int stride = gridDim.x * blockDim.x;
    for (; i < n; i += stride) dst[i] = src[i];
}

// ---------------------------------------------------------------------------
// Kernel 3: per-group attention, contrib, unified write + zeroing.
// ---------------------------------------------------------------------------
__global__ __launch_bounds__(256) void attn_merge(
    const float* __restrict__ TE, const bf16_t* __restrict__ Cq,
    const float* __restrict__ bias, const int* __restrict__ sidx,
    float* __restrict__ out)
{
    __shared__ __align__(16) bf16_t qk[Ktok][Ncols];   // 24 KB bf16 q|k rows
    __shared__ float sc[NHEAD][Ktok][Ktok];            // scores -> attn
    __shared__ float cN[Ktok];
    __shared__ int   validS[Ktok];

    const int g   = blockIdx.x;
    const int b   = g >> 7;
    const int w   = g & (Wdim - 1);
    const int tid = threadIdx.x;

    if (tid < Ktok) {
        const int id = sidx[g*Ktok + tid];
        validS[tid] = (id != 0) || (w == 0 && tid == 0);
    }
    __syncthreads();

    int valid[Ktok], idxv[Ktok];
    #pragma unroll
    for (int kk = 0; kk < Ktok; kk++) { valid[kk] = validS[kk]; idxv[kk] = sidx[g*Ktok + kk]; }

    // stage q|k rows into LDS as bf16 (bias substituted for invalid rows)
    #pragma unroll
    for (int it = 0; it < Ktok; it++) {
        if (valid[it]) {
            *(short8*)(void*)&qk[it][tid*8] =
                *(const short8*)(const void*)&Cq[(size_t)(g*Ktok + it)*Ncols + tid*8];
        } else {
            const float4 lo = *(const float4*)(bias + tid*8);
            const float4 hi = *(const float4*)(bias + tid*8 + 4);
            *(short8*)(void*)&qk[it][tid*8] = cvt8(lo, hi);
        }
    }
    __syncthreads();

    // scores[n][i][j] = q_i(head n) . k_j(head n) / 8 + pair
    for (int t = tid; t < NHEAD*Ktok*Ktok; t += 256) {
        const int n = t / (Ktok*Ktok);
        const int pr = t % (Ktok*Ktok);
        const int i = pr / Ktok, j = pr % Ktok;
        const bf16_t* qp = &qk[i][n*HDdim];
        const bf16_t* kp = &qk[j][Hdim + n*HDdim];
        float dot = 0.f;
        #pragma unroll
        for (int c = 0; c < 8; c++) {
            const short8 q8 = *(const short8*)(const void*)(qp + c*8);
            const short8 k8 = *(const short8*)(const void*)(kp + c*8);
            #pragma unroll
            for (int e = 0; e < 8; e++) dot += b2f(q8[e]) * b2f(k8[e]);
        }
        sc[n][i][j] = dot * 0.125f + ((valid[i] && valid[j]) ? 1.0f : 0.0f);
    }
    __syncthreads();

    // softmax over j (in place)
    if (tid < NHEAD*Ktok) {
        const int n = tid / Ktok, i = tid % Ktok;
        float mx = -1e30f;
        #pragma unroll
        for (int j = 0; j < Ktok; j++) mx = fmaxf(mx, sc[n][i][j]);
        float e[Ktok], sum = 0.f;
        #pragma unroll
        for (int j = 0; j < Ktok; j++) { e[j] = __expf(sc[n][i][j] - mx); sum += e[j]; }
        const float inv = 1.0f / sum;
        #pragma unroll
        for (int j = 0; j < Ktok; j++) sc[n][i][j] = e[j] * inv;
    }
    __syncthreads();

    // contrib: cb[j] = sum_i pair[i][j] * mean_n attn[n][i][j]; normalize
    if (tid == 0) {
        float cb[Ktok], tot = 0.f;
        #pragma unroll
        for (int j = 0; j < Ktok; j++) cb[j] = 0.f;
        #pragma unroll
        for (int i = 0; i < Ktok; i++) {
            if (!valid[i]) continue;
            #pragma unroll
            for (int j = 0; j < Ktok; j++) {
                if (!valid[j]) continue;
                float s = 0.f;
                #pragma unroll
                for (int n = 0; n < NHEAD; n++) s += sc[n][i][j];
                cb[j] += s * (1.0f/NHEAD);
            }
        }
        #pragma unroll
        for (int j = 0; j < Ktok; j++) tot += cb[j];
        const float inv = 1.0f / (tot + 1e-8f);
        #pragma unroll
        for (int j = 0; j < Ktok; j++) cN[j] = cb[j] * inv;
    }
    __syncthreads();

    float cw[Ktok];
    #pragma unroll
    for (int kk = 0; kk < Ktok; kk++) cw[kk] = cN[kk];

    // unified row -> out[b, idx[g,0], :]
    const int c4 = tid * 4;
    const size_t rowOut = ((size_t)b*Sdim + idxv[0]) * Hdim;
    float4 u = {0.f, 0.f, 0.f, 0.f};
    #pragma unroll
    for (int kk = 0; kk < Ktok; kk++) {
        const float4 v = *(const float4*)(TE + ((size_t)b*Sdim + idxv[kk])*Hdim + c4);
        u.x += cw[kk]*v.x; u.y += cw[kk]*v.y; u.z += cw[kk]*v.z; u.w += cw[kk]*v.w;
    }
    *(float4*)(out + rowOut + c4) = u;

    // zero absorbed rows (k >= 1, valid)
    const float4 z = {0.f, 0.f, 0.f, 0.f};
    #pragma unroll
    for (int kk = 1; kk < Ktok; kk++) {
        if (valid[kk]) {
            *(float4*)(out + ((size_t)b*Sdim + idxv[kk])*Hdim + c4) = z;
        }
    }
}

// ---------------------------------------------------------------------------
extern "C" void kernel_launch(void* const* d_in, const int* in_sizes, int n_in,
                              void* d_out, int out_size, void* d_ws, size_t ws_size,
                              hipStream_t stream)
{
    (void)in_sizes; (void)n_in; (void)out_size;
    const float* TE   = (const float*)d_in[0];
    const float* Wt   = (const float*)d_in[1];
    const float* bias = (const float*)d_in[2];
    const int*   sidx = (const int*)d_in[3];
    float*  out  = (float*)d_out;

    // ws layout: Cq (96 MiB) | Xa (48 MiB) | Wb (4 MiB)
    const size_t CQ_BYTES = (size_t)Mrows * Ncols * 2;     // 100663296
    const size_t XA_BYTES = (size_t)Mrows * Hdim * 2;      //  50331648
    const size_t WB_BYTES = (size_t)Ncols * Hdim * 2;      //   4194304
    bf16_t* Cq = (bf16_t*)d_ws;
    bf16_t* Xa = (bf16_t*)((char*)d_ws + CQ_BYTES);
    bf16_t* Wb = (bf16_t*)((char*)d_ws + CQ_BYTES + XA_BYTES);

    if (ws_size >= CQ_BYTES + XA_BYTES + WB_BYTES) {
        gather_cvt<<<CVTROWS, 256, 0, stream>>>(TE, Wt, sidx, Xa, Wb);
        gemm_8ph<<<dim3((Mrows/BMg)*(Ncols/BNg)), dim3(512), 0, stream>>>(Xa, Wb, bias, Cq);
    } else {
        dim3 gg(Mrows/128, Ncols/128);  // 192 x 16
        gemm_qk<<<gg, dim3(256), 0, stream>>>(TE, Wt, bias, sidx, Cq);
    }
    copy_te<<<4096, 256, 0, stream>>>((const uint4*)TE, (uint4*)d_out,
                                      (Bdim*Sdim*Hdim)/4);
    attn_merge<<<Lgrp, 256, 0, stream>>>(TE, Cq, bias, sidx, out);
}

// Round 3
// 400.869 us; speedup vs baseline: 1.1715x; 1.0441x over previous
//
#include <hip/hip_runtime.h>
#include <hip/hip_bf16.h>
#include <stdint.h>
#include <stddef.h>

#define Bdim  32
#define Sdim  1024
#define Hdim  1024
#define Wdim  128
#define Ktok  6
#define NHEAD 16
#define HDdim 64
#define Lgrp  (Bdim*Wdim)      // 4096 groups
#define Mrows (Lgrp*Ktok)      // 24576 gathered rows
#define Ncols (2*Hdim)         // 2048 (q|k)
#define CVTROWS (Mrows + Ncols)

// 8-phase GEMM geometry (m201 template, 2-barrier variant)
#define BMg 256
#define BNg 256
#define BKg 64
#define NKT (Hdim/BKg)         // 16 K-tiles

typedef __attribute__((ext_vector_type(8))) short short8;
typedef __attribute__((ext_vector_type(4))) short short4_t;
typedef __attribute__((ext_vector_type(4))) float floatx4;
typedef __hip_bfloat16 bf16_t;

typedef unsigned int u32_g __attribute__((address_space(1)));
typedef unsigned int u32_l __attribute__((address_space(3)));

__device__ __forceinline__ void gld_lds16(const void* g, void* l) {
    __builtin_amdgcn_global_load_lds((const u32_g*)g, (u32_l*)l, 16, 0, 0);
}

__device__ __forceinline__ float b2f(short s) {
    union { float f; unsigned u; } x; x.u = ((unsigned)(unsigned short)s) << 16; return x.f;
}

// pack 8 fp32 -> 8 bf16 (RNE) in a 16B vector
__device__ __forceinline__ short8 cvt8(const float4 lo, const float4 hi) {
    union { short8 s; bf16_t h[8]; } u;
    u.h[0] = __float2bfloat16(lo.x); u.h[1] = __float2bfloat16(lo.y);
    u.h[2] = __float2bfloat16(lo.z); u.h[3] = __float2bfloat16(lo.w);
    u.h[4] = __float2bfloat16(hi.x); u.h[5] = __float2bfloat16(hi.y);
    u.h[6] = __float2bfloat16(hi.z); u.h[7] = __float2bfloat16(hi.w);
    return u.s;
}

// ---------------------------------------------------------------------------
// st_16x32 swizzled half-tile addressing (128 rows x 64 cols bf16, 16 KiB).
// ---------------------------------------------------------------------------
__device__ __forceinline__ int lds_ro(int row, int col) {
    const int sub = ((row >> 4) << 1) | (col >> 5);
    const int c   = (col & 31) ^ (((row >> 3) & 1) << 4);
    return (sub << 10) | ((row & 15) << 6) | (c << 1);
}
// inverse map: linear staging byte offset p -> logical (row,col); the GLOBAL
// source address is pre-swizzled so global_load_lds dest stays linear.
__device__ __forceinline__ void stg_map(int p, int& row, int& col) {
    const int r16 = (p >> 6) & 15;
    int c = (p >> 1) & 31;
    c ^= ((r16 >> 3) & 1) << 4;
    row = ((p >> 11) << 4) | r16;
    col = (((p >> 10) & 1) << 5) | c;
}

// ---------------------------------------------------------------------------
// Kernel -1: zero the 32 KiB zflag table (replaces hipMemsetAsync — G9:
// only kernel launches inside kernel_launch).
// ---------------------------------------------------------------------------
__global__ void zero_zf(unsigned int* __restrict__ zf)
{
    zf[blockIdx.x * 256 + threadIdx.x] = 0u;
}

// ---------------------------------------------------------------------------
// Kernel 0 (fast path): gather A rows + convert everything to bf16 once.
// Also builds the per-(b,s) zero-flag table for absorbed rows (k>=1, valid).
// ---------------------------------------------------------------------------
__global__ void gather_cvt(const float* __restrict__ TE, const float* __restrict__ Wt,
                           const int* __restrict__ sidx,
                           bf16_t* __restrict__ Xa, bf16_t* __restrict__ Wb,
                           unsigned char* __restrict__ zflag)
{
    const int r = blockIdx.x;
    const int t = threadIdx.x;
    const float* src;
    bf16_t* dst;
    if (r < Mrows) {
        const int id = sidx[r];
        const int b  = r / (Wdim*Ktok);
        src = TE + ((size_t)b*Sdim + id)*Hdim;
        dst = Xa + (size_t)r*Hdim;
        // absorbed row: k>=1 and valid (id!=0 <=> valid for k>=1)
        if (t == 0 && (r % Ktok) >= 1 && id != 0) zflag[b*Sdim + id] = 1;
    } else {
        src = Wt + (size_t)(r - Mrows)*Hdim;
        dst = Wb + (size_t)(r - Mrows)*Hdim;
    }
    const float4 v = *(const float4*)(src + t*4);
    union { short4_t s; bf16_t h[4]; } u;
    u.h[0] = __float2bfloat16(v.x); u.h[1] = __float2bfloat16(v.y);
    u.h[2] = __float2bfloat16(v.z); u.h[3] = __float2bfloat16(v.w);
    *(short4_t*)(dst + t*4) = u.s;
}

// ---------------------------------------------------------------------------
// Kernel 1 (fast path): 256x256 pipelined bf16 GEMM, 2 barriers per K-tile.
// 8 waves (2M x 4N), BK=64, 128 KiB LDS as [2 dbuf][A/B][2 half][16 KiB].
// MMA order Q00,Q01 | barrier | Q11,Q10; STAGEs: A1(u+1),B0(u+1) before the
// mid barrier (into nb), A0(u+2),B1(u+2) after it (into bf slots whose tile-u
// data was consumed by Q00/Q01 — all waves provably past those reads).
// Counted vmcnt(4) at tile end keeps {A0,B1}(u+2) in flight across barriers.
// Compiler places all lgkmcnt for ds_read->MFMA (m97 evidence, rule #18).
// ---------------------------------------------------------------------------
__global__ __launch_bounds__(512, 2) void gemm_8ph(
    const bf16_t* __restrict__ Xa, const bf16_t* __restrict__ Wb,
    const float* __restrict__ bias, bf16_t* __restrict__ Cq)
{
    __shared__ __align__(16) char lds[2][2][2][16384];
    const int tid  = threadIdx.x;
    const int lane = tid & 63;
    const int wv   = tid >> 6;
    const int wr   = wv >> 2;      // 0..1
    const int wc   = wv & 3;       // 0..3
    const int fr   = lane & 15;
    const int fq   = lane >> 4;

    // bijective XCD swizzle (768 % 8 == 0)
    const int cpx  = gridDim.x >> 3;
    const int orig = blockIdx.x;
    const int swz  = (orig & 7) * cpx + (orig >> 3);
    const int tileM = (swz >> 3) * BMg;
    const int tileN = (swz & 7) * BNg;

    int r0, c0, r1, c1;
    stg_map(tid * 16, r0, c0);
    stg_map(8192 + tid * 16, r1, c1);

    const bf16_t* srcA = Xa + (size_t)tileM * Hdim;
    const bf16_t* srcB = Wb + (size_t)tileN * Hdim;

    int aoff[4][2], boff[2][2];
    #pragma unroll
    for (int mi = 0; mi < 4; mi++)
        #pragma unroll
        for (int ks = 0; ks < 2; ks++)
            aoff[mi][ks] = lds_ro(wr*64 + mi*16 + fr, ks*32 + fq*8);
    #pragma unroll
    for (int ni = 0; ni < 2; ni++)
        #pragma unroll
        for (int ks = 0; ks < 2; ks++)
            boff[ni][ks] = lds_ro(wc*32 + ni*16 + fr, ks*32 + fq*8);

    short8 a[4][2], b[2][2];
    floatx4 acc[2][2][4][2] = {};

#define STAGE(bufi, isB, half, kt) do { \
        const bf16_t* _s = (isB) ? srcB : srcA; \
        char* _d = &lds[(bufi)][(isB)][(half)][0]; \
        const int _kb = (kt) * BKg; \
        gld_lds16(_s + (size_t)((half)*128 + r0) * Hdim + _kb + c0, _d + tid*16); \
        gld_lds16(_s + (size_t)((half)*128 + r1) * Hdim + _kb + c1, _d + 8192 + tid*16); \
    } while (0)

#define LDAf(bufi, qr) do { \
        const char* _sA = &lds[(bufi)][0][(qr)][0]; \
        _Pragma("unroll") \
        for (int mi = 0; mi < 4; mi++) { \
            a[mi][0] = *(const short8*)(const void*)(_sA + aoff[mi][0]); \
            a[mi][1] = *(const short8*)(const void*)(_sA + aoff[mi][1]); \
        } \
    } while (0)

#define LDBf(bufi, qc) do { \
        const char* _sB = &lds[(bufi)][1][(qc)][0]; \
        _Pragma("unroll") \
        for (int ni = 0; ni < 2; ni++) { \
            b[ni][0] = *(const short8*)(const void*)(_sB + boff[ni][0]); \
            b[ni][1] = *(const short8*)(const void*)(_sB + boff[ni][1]); \
        } \
    } while (0)

#define MMA(qr, qc) do { \
        __builtin_amdgcn_s_setprio(1); \
        _Pragma("unroll") \
        for (int mi = 0; mi < 4; mi++) \
            _Pragma("unroll") \
            for (int ni = 0; ni < 2; ni++) { \
                acc[qr][qc][mi][ni] = __builtin_amdgcn_mfma_f32_16x16x32_bf16( \
                    a[mi][0], b[ni][0], acc[qr][qc][mi][ni], 0, 0, 0); \
                acc[qr][qc][mi][ni] = __builtin_amdgcn_mfma_f32_16x16x32_bf16( \
                    a[mi][1], b[ni][1], acc[qr][qc][mi][ni], 0, 0, 0); \
            } \
        __builtin_amdgcn_s_setprio(0); \
    } while (0)

    // prologue: tile0 all halves + {A0,B1}(1); last 4 issued stay in flight
    STAGE(0, 0, 0, 0);
    STAGE(0, 1, 0, 0);
    STAGE(0, 0, 1, 0);
    STAGE(0, 1, 1, 0);
    STAGE(1, 0, 0, 1);
    STAGE(1, 1, 1, 1);
    asm volatile("s_waitcnt vmcnt(4)" ::: "memory");
    __builtin_amdgcn_s_barrier();

    for (int u = 0; u < NKT; ++u) {
        const int bf = u & 1;
        const int nb = bf ^ 1;
        // Q00: read A0,B0 (12 ds_reads); stage A1(u+1) into nb
        LDAf(bf, 0);
        LDBf(bf, 0);
        if (u + 1 < NKT) STAGE(nb, 0, 1, u + 1);
        MMA(0, 0);
        // Q01: read B1 (4 ds_reads); stage B0(u+1) into nb
        LDBf(bf, 1);
        if (u + 1 < NKT) STAGE(nb, 1, 0, u + 1);
        MMA(0, 1);
        // mid barrier: every wave has consumed A0- and B1-slot LDS data
        __builtin_amdgcn_s_barrier();
        // Q11: read A1 (8 ds_reads); stage A0(u+2), B1(u+2) into bf
        LDAf(bf, 1);
        if (u + 2 < NKT) { STAGE(bf, 0, 0, u + 2); STAGE(bf, 1, 1, u + 2); }
        MMA(1, 1);
        // Q10: re-read B0 (4 ds_reads)
        LDBf(bf, 0);
        MMA(1, 0);
        // counted wait: tile u+1 fully landed; {A0,B1}(u+2) stay in flight
        if (u + 2 < NKT)      asm volatile("s_waitcnt vmcnt(4)" ::: "memory");
        else if (u + 1 < NKT) asm volatile("s_waitcnt vmcnt(0)" ::: "memory");
        __builtin_amdgcn_s_barrier();
    }

    #pragma unroll
    for (int qr = 0; qr < 2; qr++)
      #pragma unroll
      for (int qc = 0; qc < 2; qc++)
        #pragma unroll
        for (int ni = 0; ni < 2; ni++) {
            const int col = tileN + qc*128 + wc*32 + ni*16 + fr;
            const float bv = bias[col];
            #pragma unroll
            for (int mi = 0; mi < 4; mi++)
              #pragma unroll
              for (int j = 0; j < 4; j++) {
                const int row = tileM + qr*128 + wr*64 + mi*16 + fq*4 + j;
                Cq[(size_t)row * Ncols + col] = __float2bfloat16(acc[qr][qc][mi][ni][j] + bv);
              }
        }
#undef STAGE
#undef LDAf
#undef LDBf
#undef MMA
}

// ---------------------------------------------------------------------------
// Kernel 1 (fallback, ws too small): fused gather+cvt GEMM (128-tile).
// ---------------------------------------------------------------------------
__global__ __launch_bounds__(256, 2) void gemm_qk(
    const float* __restrict__ TE, const float* __restrict__ Wt,
    const float* __restrict__ bias, const int* __restrict__ sidx,
    bf16_t* __restrict__ Cq)
{
    __shared__ __align__(16) bf16_t As[128*32];
    __shared__ __align__(16) bf16_t Bs[128*32];
    const int tid  = threadIdx.x;
    const int wv   = tid >> 6;
    const int lane = tid & 63;
    const int tileM = blockIdx.x * 128;
    const int tileN = blockIdx.y * 128;

    const int r0 = wv*32 + (lane>>2);
    const int r1 = r0 + 16;
    const int c8 = (lane&3)*8;

    const int m0 = tileM + r0;
    const int m1 = tileM + r1;
    const float* pA0 = TE + ((size_t)(m0/768)*Sdim + sidx[m0])*Hdim + c8;
    const float* pA1 = TE + ((size_t)(m1/768)*Sdim + sidx[m1])*Hdim + c8;
    const float* pB0 = Wt + (size_t)(tileN + r0)*Hdim + c8;
    const float* pB1 = Wt + (size_t)(tileN + r1)*Hdim + c8;
    bf16_t* lA0 = &As[r0*32 + c8];
    bf16_t* lA1 = &As[r1*32 + c8];
    bf16_t* lB0 = &Bs[r0*32 + c8];
    bf16_t* lB1 = &Bs[r1*32 + c8];

    const int wm = (wv & 1)*64;
    const int wn = (wv >> 1)*64;
    const int fr = lane & 15;
    const int fq = lane >> 4;

    floatx4 acc[4][4] = {};

    for (int k0 = 0; k0 < Hdim; k0 += 32) {
        const float4 a0l = *(const float4*)(pA0 + k0);
        const float4 a0h = *(const float4*)(pA0 + k0 + 4);
        const float4 a1l = *(const float4*)(pA1 + k0);
        const float4 a1h = *(const float4*)(pA1 + k0 + 4);
        const float4 b0l = *(const float4*)(pB0 + k0);
        const float4 b0h = *(const float4*)(pB0 + k0 + 4);
        const float4 b1l = *(const float4*)(pB1 + k0);
        const float4 b1h = *(const float4*)(pB1 + k0 + 4);
        *(short8*)(void*)lA0 = cvt8(a0l, a0h);
        *(short8*)(void*)lA1 = cvt8(a1l, a1h);
        *(short8*)(void*)lB0 = cvt8(b0l, b0h);
        *(short8*)(void*)lB1 = cvt8(b1l, b1h);
        __syncthreads();
        short8 a[4], b[4];
        #pragma unroll
        for (int mi = 0; mi < 4; mi++)
            a[mi] = *(const short8*)(const void*)&As[(wm + mi*16 + fr)*32 + fq*8];
        #pragma unroll
        for (int ni = 0; ni < 4; ni++)
            b[ni] = *(const short8*)(const void*)&Bs[(wn + ni*16 + fr)*32 + fq*8];
        #pragma unroll
        for (int mi = 0; mi < 4; mi++)
            #pragma unroll
            for (int ni = 0; ni < 4; ni++)
                acc[mi][ni] = __builtin_amdgcn_mfma_f32_16x16x32_bf16(
                    a[mi], b[ni], acc[mi][ni], 0, 0, 0);
        __syncthreads();
    }

    #pragma unroll
    for (int ni = 0; ni < 4; ni++) {
        const int col = tileN + wn + ni*16 + fr;
        const float bv = bias[col];
        #pragma unroll
        for (int mi = 0; mi < 4; mi++) {
            #pragma unroll
            for (int r = 0; r < 4; r++) {
                const int row = tileM + wm + mi*16 + fq*4 + r;
                Cq[(size_t)row * Ncols + col] = __float2bfloat16(acc[mi][ni][r] + bv);
            }
        }
    }
}

// ---------------------------------------------------------------------------
// Kernel 2: out = token_embeddings, except absorbed rows -> zeros (flagged).
// 256-thread block covers a 1024-float row chunk, so the flag branch is
// wave-uniform; zeroed rows skip the HBM read entirely.
// ---------------------------------------------------------------------------
__global__ void copy_te(const uint4* __restrict__ src, uint4* __restrict__ dst,
                        const unsigned char* __restrict__ zflag, int n)
{
    int i = blockIdx.x * blockDim.x + threadIdx.x;
    const int stride = gridDim.x * blockDim.x;
    const uint4 z = {0u, 0u, 0u, 0u};
    for (; i < n; i += stride) {
        if (zflag != nullptr && zflag[i >> 8]) dst[i] = z;
        else dst[i] = src[i];
    }
}

// ---------------------------------------------------------------------------
// Kernel 3: per-group attention, contrib, unified write (+ optional zeroing).
// ---------------------------------------------------------------------------
__global__ __launch_bounds__(256) void attn_merge(
    const float* __restrict__ TE, const bf16_t* __restrict__ Cq,
    const float* __restrict__ bias, const int* __restrict__ sidx,
    float* __restrict__ out, int zero_rows)
{
    __shared__ __align__(16) bf16_t qk[Ktok][Ncols];   // 24 KB bf16 q|k rows
    __shared__ float sc[NHEAD][Ktok][Ktok];            // scores -> attn
    __shared__ float cN[Ktok];
    __shared__ int   validS[Ktok];

    const int g   = blockIdx.x;
    const int b   = g >> 7;
    const int w   = g & (Wdim - 1);
    const int tid = threadIdx.x;

    if (tid < Ktok) {
        const int id = sidx[g*Ktok + tid];
        validS[tid] = (id != 0) || (w == 0 && tid == 0);
    }
    __syncthreads();

    int valid[Ktok], idxv[Ktok];
    #pragma unroll
    for (int kk = 0; kk < Ktok; kk++) { valid[kk] = validS[kk]; idxv[kk] = sidx[g*Ktok + kk]; }

    // stage q|k rows into LDS as bf16 (bias substituted for invalid rows)
    #pragma unroll
    for (int it = 0; it < Ktok; it++) {
        if (valid[it]) {
            *(short8*)(void*)&qk[it][tid*8] =
                *(const short8*)(const void*)&Cq[(size_t)(g*Ktok + it)*Ncols + tid*8];
        } else {
            const float4 lo = *(const float4*)(bias + tid*8);
            const float4 hi = *(const float4*)(bias + tid*8 + 4);
            *(short8*)(void*)&qk[it][tid*8] = cvt8(lo, hi);
        }
    }
    __syncthreads();

    // scores[n][i][j] = q_i(head n) . k_j(head n) / 8 + pair
    for (int t = tid; t < NHEAD*Ktok*Ktok; t += 256) {
        const int n = t / (Ktok*Ktok);
        const int pr = t % (Ktok*Ktok);
        const int i = pr / Ktok, j = pr % Ktok;
        const bf16_t* qp = &qk[i][n*HDdim];
        const bf16_t* kp = &qk[j][Hdim + n*HDdim];
        float dot = 0.f;
        #pragma unroll
        for (int c = 0; c < 8; c++) {
            const short8 q8 = *(const short8*)(const void*)(qp + c*8);
            const short8 k8 = *(const short8*)(const void*)(kp + c*8);
            #pragma unroll
            for (int e = 0; e < 8; e++) dot += b2f(q8[e]) * b2f(k8[e]);
        }
        sc[n][i][j] = dot * 0.125f + ((valid[i] && valid[j]) ? 1.0f : 0.0f);
    }
    __syncthreads();

    // softmax over j (in place)
    if (tid < NHEAD*Ktok) {
        const int n = tid / Ktok, i = tid % Ktok;
        float mx = -1e30f;
        #pragma unroll
        for (int j = 0; j < Ktok; j++) mx = fmaxf(mx, sc[n][i][j]);
        float e[Ktok], sum = 0.f;
        #pragma unroll
        for (int j = 0; j < Ktok; j++) { e[j] = __expf(sc[n][i][j] - mx); sum += e[j]; }
        const float inv = 1.0f / sum;
        #pragma unroll
        for (int j = 0; j < Ktok; j++) sc[n][i][j] = e[j] * inv;
    }
    __syncthreads();

    // contrib: cb[j] = sum_i pair[i][j] * mean_n attn[n][i][j]; normalize
    if (tid == 0) {
        float cb[Ktok], tot = 0.f;
        #pragma unroll
        for (int j = 0; j < Ktok; j++) cb[j] = 0.f;
        #pragma unroll
        for (int i = 0; i < Ktok; i++) {
            if (!valid[i]) continue;
            #pragma unroll
            for (int j = 0; j < Ktok; j++) {
                if (!valid[j]) continue;
                float s = 0.f;
                #pragma unroll
                for (int n = 0; n < NHEAD; n++) s += sc[n][i][j];
                cb[j] += s * (1.0f/NHEAD);
            }
        }
        #pragma unroll
        for (int j = 0; j < Ktok; j++) tot += cb[j];
        const float inv = 1.0f / (tot + 1e-8f);
        #pragma unroll
        for (int j = 0; j < Ktok; j++) cN[j] = cb[j] * inv;
    }
    __syncthreads();

    float cw[Ktok];
    #pragma unroll
    for (int kk = 0; kk < Ktok; kk++) cw[kk] = cN[kk];

    // unified row -> out[b, idx[g,0], :]
    const int c4 = tid * 4;
    const size_t rowOut = ((size_t)b*Sdim + idxv[0]) * Hdim;
    float4 u = {0.f, 0.f, 0.f, 0.f};
    #pragma unroll
    for (int kk = 0; kk < Ktok; kk++) {
        const float4 v = *(const float4*)(TE + ((size_t)b*Sdim + idxv[kk])*Hdim + c4);
        u.x += cw[kk]*v.x; u.y += cw[kk]*v.y; u.z += cw[kk]*v.z; u.w += cw[kk]*v.w;
    }
    *(float4*)(out + rowOut + c4) = u;

    // zero absorbed rows (only when copy_te didn't already do it)
    if (zero_rows) {
        const float4 z = {0.f, 0.f, 0.f, 0.f};
        #pragma unroll
        for (int kk = 1; kk < Ktok; kk++) {
            if (valid[kk]) {
                *(float4*)(out + ((size_t)b*Sdim + idxv[kk])*Hdim + c4) = z;
            }
        }
    }
}

// ---------------------------------------------------------------------------
extern "C" void kernel_launch(void* const* d_in, const int* in_sizes, int n_in,
                              void* d_out, int out_size, void* d_ws, size_t ws_size,
                              hipStream_t stream)
{
    (void)in_sizes; (void)n_in; (void)out_size;
    const float* TE   = (const float*)d_in[0];
    const float* Wt   = (const float*)d_in[1];
    const float* bias = (const float*)d_in[2];
    const int*   sidx = (const int*)d_in[3];
    float*  out  = (float*)d_out;

    // ws layout: Cq (96 MiB) | Xa (48 MiB) | Wb (4 MiB) | zflag (32 KiB)
    const size_t CQ_BYTES = (size_t)Mrows * Ncols * 2;     // 100663296
    const size_t XA_BYTES = (size_t)Mrows * Hdim * 2;      //  50331648
    const size_t WB_BYTES = (size_t)Ncols * Hdim * 2;      //   4194304
    const size_t ZF_BYTES = (size_t)Bdim * Sdim;           //      32768
    bf16_t* Cq = (bf16_t*)d_ws;
    bf16_t* Xa = (bf16_t*)((char*)d_ws + CQ_BYTES);
    bf16_t* Wb = (bf16_t*)((char*)d_ws + CQ_BYTES + XA_BYTES);
    unsigned char* zf = (unsigned char*)((char*)d_ws + CQ_BYTES + XA_BYTES + WB_BYTES);

    if (ws_size >= CQ_BYTES + XA_BYTES + WB_BYTES + ZF_BYTES) {
        zero_zf<<<ZF_BYTES/1024, 256, 0, stream>>>((unsigned int*)zf);
        gather_cvt<<<CVTROWS, 256, 0, stream>>>(TE, Wt, sidx, Xa, Wb, zf);
        gemm_8ph<<<dim3((Mrows/BMg)*(Ncols/BNg)), dim3(512), 0, stream>>>(Xa, Wb, bias, Cq);
        copy_te<<<4096, 256, 0, stream>>>((const uint4*)TE, (uint4*)d_out, zf,
                                          (Bdim*Sdim*Hdim)/4);
        attn_merge<<<Lgrp, 256, 0, stream>>>(TE, Cq, bias, sidx, out, 0);
    } else {
        dim3 gg(Mrows/128, Ncols/128);  // 192 x 16
        gemm_qk<<<gg, dim3(256), 0, stream>>>(TE, Wt, bias, sidx, Cq);
        copy_te<<<4096, 256, 0, stream>>>((const uint4*)TE, (uint4*)d_out, nullptr,
                                          (Bdim*Sdim*Hdim)/4);
        attn_merge<<<Lgrp, 256, 0, stream>>>(TE, Cq, bias, sidx, out, 1);
    }
}